// Round 3
// baseline (157.529 us; speedup 1.0000x reference)
//
#include <hip/hip_runtime.h>
#include <stdint.h>

// DCNv2 forward, MI355X — R15: pin the pipeline + 8 waves in fused_gemm.
//  R14 post-mortem: lgkm-only barrier REGRESSED (50.6->58.1us) => drain was
//  not the stall. Real evidence: VGPR_Count=84 ~= acc(64)+afr(16)+temps —
//  the compiler COLLAPSED the software pipeline (sank prefetch loads to
//  their consumers), exposing serial L2 latency per tile with only
//  1 wave/SIMD. R15:
//   (1) gathers issued via inline-asm global_load_dwordx2 (issue-pinned,
//       cannot sink); per-tile explicit `s_waitcnt vmcnt(0) lgkmcnt(0);
//       s_barrier` + sched_barrier(0) (rule #18) makes them complete
//       before next-tile consumption — no hand waitcnt tracking.
//   (2) B staged by global_load_lds into a double-buffered LDS tile
//       (issued at tile top, drained at the barrier) — removes the 32-VGPR
//       B register set and its latency chain.
//   (3) 512 threads / 8 waves (2M x 4N) -> 2 waves/SIMD to cover residual
//       drain stalls. acc[2][4], ~110 VGPR, launch_bounds(512,2).
//  K0/K1/K2 unchanged. Workspace ~31 MB.

#define CIN 256
#define COUT 256
#define HWS 4096      // H*W
#define MTOT 16384    // B*H*W
#define KTOT 2304     // CIN*9
#define SPLITK 8

typedef __attribute__((ext_vector_type(8))) short bf16x8;
typedef __attribute__((ext_vector_type(4))) float f32x4;

__device__ __forceinline__ unsigned short f2bf(float f) {
  unsigned int u = __float_as_uint(f);
  unsigned int r = (u + 0x7fffu + ((u >> 16) & 1u)) >> 16;
  return (unsigned short)r;
}
__device__ __forceinline__ float bf2f(unsigned short u) {
  return __uint_as_float(((unsigned int)u) << 16);
}

__device__ __forceinline__ void gload_lds16(const void* g, void* l) {
  __builtin_amdgcn_global_load_lds((const __attribute__((address_space(1))) void*)g,
                                   (__attribute__((address_space(3))) void*)l, 16, 0, 0);
}

// Issue-pinned 8-byte gather: asm volatile cannot be sunk by the scheduler.
// Result is NOT compiler-wait-tracked; correctness comes from the per-tile
// vmcnt(0) drain barrier between issue and consumption.
__device__ __forceinline__ ushort4 gload8_async(const unsigned short* p) {
  ushort4 d;
  asm volatile("global_load_dwordx2 %0, %1, off" : "=v"(d) : "v"(p));
  return d;
}

// Full-drain barrier + compiler scheduling fence (rule #18: VALU consumers
// of asm-defined regs are not ordered by "memory" clobber alone).
__device__ __forceinline__ void barrier_drain() {
  asm volatile("s_waitcnt vmcnt(0) lgkmcnt(0)\n\ts_barrier" ::: "memory");
  __builtin_amdgcn_sched_barrier(0);
}

// ---------------- K0: fused transpose + weight prep (WB2 frag-block order) ----------------
__global__ __launch_bounds__(256) void prep_and_transpose(const float* __restrict__ x,
                                                          const float* __restrict__ w,
                                                          const float* __restrict__ pw,
                                                          unsigned short* __restrict__ xt,
                                                          unsigned short* __restrict__ WB,
                                                          unsigned short* __restrict__ PWs,
                                                          unsigned short* __restrict__ zerop) {
  __shared__ float tile[32][33];
  int bid = blockIdx.x;
  if (bid < 4096) {
    int b = bid >> 10;
    int rest = bid & 1023;
    int hw0 = (rest & 127) * 32;
    int c0 = ((rest >> 7) & 7) * 32;
    int tx = threadIdx.x & 31, ty = threadIdx.x >> 5;
    for (int i = ty; i < 32; i += 8)
      tile[i][tx] = x[(size_t)(b * CIN + c0 + i) * HWS + hw0 + tx];
    __syncthreads();
    for (int r = ty; r < 32; r += 8)
      xt[(size_t)(b * HWS + hw0 + r) * CIN + c0 + tx] = f2bf(tile[tx][r]);
  } else {
    int idx = (bid - 4096) * 256 + threadIdx.x;
    if (idx < 512)
      *(uint4*)(zerop + idx * 8) = make_uint4(0, 0, 0, 0);
    if (idx < KTOT * COUT) {
      // WB2[t][j][quad][row][8]: f = (((t*16+j)*4+quad)*16+row)*8+e
      int f = idx;
      int e = f & 7;
      int row = (f >> 3) & 15;
      int quad = (f >> 7) & 3;
      int j = (f >> 9) & 15;
      int t = f >> 13;                 // 0..71
      int kk = t * 32 + quad * 8 + e;
      int o = j * 16 + row;
      int k = kk >> 8, c = kk & 255;
      WB[f] = f2bf(w[o * KTOT + c * 9 + k]);
    } else {
      int f2 = idx - KTOT * COUT;   // < 2304*32
      int t_ = f2 & 7;
      int rest = f2 >> 3;
      int j = rest & 31;
      int kk = (rest >> 5) * 8 + t_;
      int k = kk >> 8, c = kk & 255;
      float v = (j < 27) ? pw[j * KTOT + c * 9 + k] : 0.0f;
      PWs[f2] = f2bf(v);
    }
  }
}

// ---------------- K1: offset conv, split-K, BM=64 ----------------
__global__ __launch_bounds__(256) void offset_conv_sk(const unsigned short* __restrict__ xt,
                                                      const unsigned short* __restrict__ PWs,
                                                      const unsigned short* __restrict__ zerop,
                                                      float* __restrict__ Pbuf) {
  __shared__ unsigned short Al[64 * 32];   // 4 KB
  __shared__ unsigned short Bl[1024];      // 2 KB
  int tid = threadIdx.x;
  int lane = tid & 63, wv = tid >> 6;
  int mt = (blockIdx.x & 7) * 32 + (blockIdx.x >> 3);   // XCD swizzle
  int m0 = mt * 64;
  int s = blockIdx.y;
  int b = m0 >> 12;
  int hw0 = m0 & 4095;
  f32x4 acc[2] = {};

  for (int tt = 0; tt < 72 / SPLITK; ++tt) {
    int t = s * (72 / SPLITK) + tt;
    int k = t >> 3, c0 = (t & 7) * 32;
    int dyk = k / 3 - 1;
    int dxk = k % 3 - 1;
    __syncthreads();
    if (tid < 128)
      gload_lds16(PWs + (size_t)t * 1024 + tid * 8, &Bl[tid * 8]);
    {
      int r = tid >> 2;
      int hw = hw0 + r;
      int h = hw >> 6, wwp = hw & 63;
      int y = h + dyk, xx = wwp + dxk;
      bool valid = ((unsigned)y < 64u) && ((unsigned)xx < 64u);
      const unsigned short* src = valid
          ? xt + ((size_t)((b << 12) + (y << 6) + xx) << 8) + c0 + (tid & 3) * 8
          : zerop;
      gload_lds16(src, &Al[tid * 8]);
    }
    __syncthreads();
    int row = lane & 15, quad = lane >> 4;
    bf16x8 af = *(const bf16x8*)&Al[(wv * 16 + row) * 32 + quad * 8];
    for (int j = 0; j < 2; ++j) {
      bf16x8 bfr = *(const bf16x8*)&Bl[(quad * 32 + j * 16 + row) * 8];
      acc[j] = __builtin_amdgcn_mfma_f32_16x16x32_bf16(af, bfr, acc[j], 0, 0, 0);
    }
  }

  int row = lane & 15, quad = lane >> 4;
  for (int j = 0; j < 2; ++j) {
    int n = j * 16 + row;
    for (int r_ = 0; r_ < 4; ++r_) {
      int m = m0 + wv * 16 + quad * 4 + r_;
      Pbuf[((size_t)s * MTOT + m) * 32 + n] = acc[j][r_];
    }
  }
}

// ---------------- K2: index prep — reduce Pbuf, compute corner idx + weights ----------------
// DIW layout: per (m, k): { int4 dI (elem offsets), float4 dW (corner weights*mask) }
__global__ __launch_bounds__(256) void index_prep(const float* __restrict__ Pbuf,
                                                  const float* __restrict__ p_bias,
                                                  int4* __restrict__ DIW) {
  int gid = blockIdx.x * 256 + threadIdx.x;   // 0..147455 == 16384*9
  int m = gid / 9;
  int k = gid - m * 9;

  float dy = p_bias[2 * k];
  float dx = p_bias[2 * k + 1];
  float mv = p_bias[18 + k];
#pragma unroll
  for (int s = 0; s < SPLITK; ++s) {
    const float* p = Pbuf + ((size_t)s * MTOT + m) * 32;
    dy += p[2 * k];
    dx += p[2 * k + 1];
    mv += p[18 + k];
  }
  float mk = 1.0f / (1.0f + __expf(-mv));

  int hw = m & 4095, h = hw >> 6, ww = hw & 63;
  float py = (float)(h - 1 + k / 3) + dy;
  float px = (float)(ww - 1 + k % 3) + dx;
  float y0f = floorf(py), x0f = floorf(px);
  float ay = py - y0f, ax = px - x0f;
  int y0 = (int)y0f, x0 = (int)x0f;

  float w00 = (1.f - ay) * (1.f - ax) * mk;
  float w01 = (1.f - ay) * ax * mk;
  float w10 = ay * (1.f - ax) * mk;
  float w11 = ay * ax * mk;

  float vy0 = ((unsigned)y0 < 64u) ? 1.f : 0.f;
  float vy1 = ((unsigned)(y0 + 1) < 64u) ? 1.f : 0.f;
  float vx0 = ((unsigned)x0 < 64u) ? 1.f : 0.f;
  float vx1 = ((unsigned)(x0 + 1) < 64u) ? 1.f : 0.f;
  w00 *= vy0 * vx0; w01 *= vy0 * vx1; w10 *= vy1 * vx0; w11 *= vy1 * vx1;

  int yc0 = min(max(y0, 0), 63), yc1 = min(max(y0 + 1, 0), 63);
  int xc0 = min(max(x0, 0), 63), xc1 = min(max(x0 + 1, 0), 63);

  DIW[(size_t)gid * 2] = make_int4((yc0 * 64 + xc0) * 256, (yc0 * 64 + xc1) * 256,
                                   (yc1 * 64 + xc0) * 256, (yc1 * 64 + xc1) * 256);
  float4 w4 = make_float4(w00, w01, w10, w11);
  ((float4*)DIW)[(size_t)gid * 2 + 1] = w4;
}

// ---------------- K3: fused sample + GEMM, 8 waves ----------------
// Block: 64 m-rows x 256 cols, 512 threads (8 waves, 2M x 4N split).
// Per k-tile t: sample 64x32 A into LDS (dbuf, asm-pinned gathers issued one
// tile ahead), B tile DMA'd via global_load_lds (dbuf, issued one tile
// ahead), both drained by the per-tile barrier. 8 MFMA per wave per tile.
__device__ __forceinline__ void bilin4(const ushort4 g00, const ushort4 g01,
                                       const ushort4 g10, const ushort4 g11,
                                       const float4 w4, unsigned short* dst) {
  ushort4 o;
  o.x = f2bf(w4.x * bf2f(g00.x) + w4.y * bf2f(g01.x) + w4.z * bf2f(g10.x) + w4.w * bf2f(g11.x));
  o.y = f2bf(w4.x * bf2f(g00.y) + w4.y * bf2f(g01.y) + w4.z * bf2f(g10.y) + w4.w * bf2f(g11.y));
  o.z = f2bf(w4.x * bf2f(g00.z) + w4.y * bf2f(g01.z) + w4.z * bf2f(g10.z) + w4.w * bf2f(g11.z));
  o.w = f2bf(w4.x * bf2f(g00.w) + w4.y * bf2f(g01.w) + w4.z * bf2f(g10.w) + w4.w * bf2f(g11.w));
  *(ushort4*)dst = o;
}

#define MFMA8(A0, A1, B0, B1, B2, B3)                                                    \
  acc[0][0] = __builtin_amdgcn_mfma_f32_16x16x32_bf16(A0, B0, acc[0][0], 0, 0, 0);       \
  acc[0][1] = __builtin_amdgcn_mfma_f32_16x16x32_bf16(A0, B1, acc[0][1], 0, 0, 0);       \
  acc[0][2] = __builtin_amdgcn_mfma_f32_16x16x32_bf16(A0, B2, acc[0][2], 0, 0, 0);       \
  acc[0][3] = __builtin_amdgcn_mfma_f32_16x16x32_bf16(A0, B3, acc[0][3], 0, 0, 0);       \
  acc[1][0] = __builtin_amdgcn_mfma_f32_16x16x32_bf16(A1, B0, acc[1][0], 0, 0, 0);       \
  acc[1][1] = __builtin_amdgcn_mfma_f32_16x16x32_bf16(A1, B1, acc[1][1], 0, 0, 0);       \
  acc[1][2] = __builtin_amdgcn_mfma_f32_16x16x32_bf16(A1, B2, acc[1][2], 0, 0, 0);       \
  acc[1][3] = __builtin_amdgcn_mfma_f32_16x16x32_bf16(A1, B3, acc[1][3], 0, 0, 0);

// Tile body T (PAR = T&1 literal). GC* = gathers for tile T+1 (issued at
// T-1, drained at T-1's barrier). GN* = gathers for tile T+2 (issued here).
//  a) asm-issue gathers(T+2) -> GN  [dI4 advanced at (T+2)&7==0]
//  b) DMA B(T+1) -> Bl[PAR^1] via global_load_lds
//  c) ds_read A-frags(T) + B-frags(T)
//  d) bilin4(GC) -> As[PAR^1]  [tile T+1's A; dW4 advanced at (T+1)&7==0]
//  e) 8 MFMA
//  f) drain barrier (vmcnt 0 + lgkm 0 + s_barrier + sched fence)
#define FITER(T, PAR, GC0, GC1, GC2, GC3, GN0, GN1, GN2, GN3)                            \
  {                                                                                      \
    if ((T) <= 69) {                                                                     \
      if ((((T) + 2) & 7) == 0) dI4 = Tbl[r][((T) + 2) >> 3][0];                         \
      int cq = (((T) + 2) & 7) * 32 + qo;                                                \
      GN0 = gload8_async(xtb + dI4.x + cq);                                              \
      GN1 = gload8_async(xtb + dI4.y + cq);                                              \
      GN2 = gload8_async(xtb + dI4.z + cq);                                              \
      GN3 = gload8_async(xtb + dI4.w + cq);                                              \
    }                                                                                    \
    if ((T) <= 70) {                                                                     \
      const unsigned short* wsrc = WB + (size_t)((T) + 1) * 8192;                        \
      unsigned short* wdst = &Bl[PAR ^ 1][0];                                            \
      gload_lds16(wsrc + tid * 8, wdst + tid * 8);                                       \
      gload_lds16(wsrc + 4096 + tid * 8, wdst + 4096 + tid * 8);                         \
    }                                                                                    \
    afr0 = *(const bf16x8*)&As[PAR][wm32 + row][quad * 8];                               \
    afr1 = *(const bf16x8*)&As[PAR][wm32 + 16 + row][quad * 8];                          \
    bfr0 = *(const bf16x8*)&Bl[PAR][bco];                                                \
    bfr1 = *(const bf16x8*)&Bl[PAR][bco + 512];                                          \
    bfr2 = *(const bf16x8*)&Bl[PAR][bco + 1024];                                         \
    bfr3 = *(const bf16x8*)&Bl[PAR][bco + 1536];                                         \
    if ((T) <= 70) {                                                                     \
      if ((((T) + 1) & 7) == 0) dW4 = *(float4*)&Tbl[r][((T) + 1) >> 3][1];              \
      bilin4(GC0, GC1, GC2, GC3, dW4, &As[PAR ^ 1][r][qo]);                              \
    }                                                                                    \
    MFMA8(afr0, afr1, bfr0, bfr1, bfr2, bfr3)                                            \
    barrier_drain();                                                                     \
  }

__global__ __launch_bounds__(512, 2) void fused_gemm(const unsigned short* __restrict__ xt,
                                                     const int4* __restrict__ DIW,
                                                     const unsigned short* __restrict__ WB,
                                                     const float* __restrict__ bias,
                                                     float* __restrict__ out) {
  __shared__ unsigned short As[2][64][40];   // 10,240 B (padded +8)
  __shared__ unsigned short Bl[2][8192];     // 32,768 B (B tile dbuf)
  __shared__ int4 Tbl[64][9][2];             // 18,432 B [r][tap]{dI, dW}

  int tid = threadIdx.x;
  int lane = tid & 63, wv = tid >> 6;         // 8 waves
  // XCD-chunked swizzle: XCD x gets 32 consecutive m-tiles.
  int mt = (blockIdx.x & 7) * 32 + (blockIdx.x >> 3);
  int mb = mt * 64;
  int b = mb >> 12;
  int hw0 = mb & 4095;
  const unsigned short* xtb = xt + ((size_t)b << 20);

  // stage index/weight table for this block's 64 rows (1152 int4)
  {
    const int4* src = DIW + (size_t)mb * 18;
    int4* dst = (int4*)Tbl;
    for (int i = tid; i < 1152; i += 512)
      gload_lds16(src + i, dst + i);
  }
  barrier_drain();

  int r = tid >> 3;        // sampler row 0..63 (8 threads/row)
  int qo = (tid & 7) * 4;  // sampler channel sub-block (4 ch, 8 B)

  int4 dI4 = Tbl[r][0][0];
  float4 dW4 = *(float4*)&Tbl[r][0][1];

  int row = lane & 15, quad = lane >> 4;
  int wm32 = (wv >> 2) * 32;                      // M-half of this wave
  int bco = (wv & 3) * 2048 + quad * 128 + row * 8;  // B frag base (shorts)

  f32x4 acc[2][4] = {};
  ushort4 gA0, gA1, gA2, gA3, gB0, gB1, gB2, gB3;
  bf16x8 afr0, afr1, bfr0, bfr1, bfr2, bfr3;

  // ---- prologue: sample tile 0 (plain loads), DMA B(0), asm gathers(1) ----
  {
    ushort4 p00 = *(const ushort4*)(xtb + dI4.x + qo);
    ushort4 p01 = *(const ushort4*)(xtb + dI4.y + qo);
    ushort4 p10 = *(const ushort4*)(xtb + dI4.z + qo);
    ushort4 p11 = *(const ushort4*)(xtb + dI4.w + qo);
    bilin4(p00, p01, p10, p11, dW4, &As[0][r][qo]);
    gload_lds16(WB + tid * 8, &Bl[0][tid * 8]);
    gload_lds16(WB + 4096 + tid * 8, &Bl[0][4096 + tid * 8]);
    // gathers for tile 1 (tap 0, c0 = 32), issue-pinned
    gB0 = gload8_async(xtb + dI4.x + 32 + qo);
    gB1 = gload8_async(xtb + dI4.y + 32 + qo);
    gB2 = gload8_async(xtb + dI4.z + 32 + qo);
    gB3 = gload8_async(xtb + dI4.w + 32 + qo);
  }
  barrier_drain();

#pragma unroll 1
  for (int t = 0; t < 72; t += 2) {
    FITER(t,     0, gB0, gB1, gB2, gB3, gA0, gA1, gA2, gA3)
    FITER(t + 1, 1, gA0, gA1, gA2, gA3, gB0, gB1, gB2, gB3)
  }

  // ---- epilogue: add bias, store NCHW ----
#pragma unroll
  for (int j = 0; j < 4; ++j) {
    int o = (wv & 3) * 64 + j * 16 + row;
    float bo = bias[o];
#pragma unroll
    for (int i = 0; i < 2; ++i) {
      int hw = hw0 + wm32 + i * 16 + quad * 4;
      float4 v;
      v.x = acc[i][j][0] + bo;
      v.y = acc[i][j][1] + bo;
      v.z = acc[i][j][2] + bo;
      v.w = acc[i][j][3] + bo;
      *(float4*)(out + (((size_t)(b * COUT + o)) << 12) + hw) = v;
    }
  }
}

// ---------------- launch ----------------
extern "C" void kernel_launch(void* const* d_in, const int* in_sizes, int n_in,
                              void* d_out, int out_size, void* d_ws, size_t ws_size,
                              hipStream_t stream) {
  const float* x        = (const float*)d_in[0];
  const float* weight   = (const float*)d_in[1];
  const float* bias     = (const float*)d_in[2];
  const float* p_weight = (const float*)d_in[3];
  const float* p_bias   = (const float*)d_in[4];
  float* out = (float*)d_out;
  char* ws = (char*)d_ws;

  // workspace layout (bytes); total ~31 MB
  const size_t OFF_XT   = 0;                          //  8,388,608  bf16 NHWC x
  const size_t OFF_WB   = OFF_XT + 8388608;           //  1,179,648  bf16 WB2
  const size_t OFF_PW   = OFF_WB + 1179648;           //    147,456  bf16
  const size_t OFF_P    = OFF_PW + 147456;            // 16,777,216  fp32 partials
  const size_t OFF_ZP   = OFF_P + 16777216;           //      8,192  zeropage
  const size_t OFF_DIW  = OFF_ZP + 8192;              //  4,718,592  idx/weight table

  unsigned short* xt    = (unsigned short*)(ws + OFF_XT);
  unsigned short* WB    = (unsigned short*)(ws + OFF_WB);
  unsigned short* PWs   = (unsigned short*)(ws + OFF_PW);
  float* Pbuf           = (float*)(ws + OFF_P);
  unsigned short* zerop = (unsigned short*)(ws + OFF_ZP);
  int4* DIW             = (int4*)(ws + OFF_DIW);

  prep_and_transpose<<<4096 + 2592, 256, 0, stream>>>(x, weight, p_weight, xt, WB, PWs, zerop);
  offset_conv_sk<<<dim3(MTOT / 64, SPLITK), 256, 0, stream>>>(xt, PWs, zerop, Pbuf);
  index_prep<<<576, 256, 0, stream>>>(Pbuf, p_bias, DIW);
  fused_gemm<<<256, 512, 0, stream>>>(xt, DIW, WB, bias, out);
}

// Round 4
// 147.398 us; speedup vs baseline: 1.0687x; 1.0687x over previous
//
#include <hip/hip_runtime.h>
#include <stdint.h>

// DCNv2 forward, MI355X — R16: overlap two chains instead of rescheduling one.
//  R14 (lgkm-only barrier) and R15 (asm-pinned pipeline, 8 waves) BOTH
//  regressed vs R13 (50.6us): hand-scheduling inside a 1-block/CU lockstep
//  structure loses to the compiler schedule every time (m131-m141 lesson).
//  R13's 1690 cyc/tile == serial chain: gather L2 latency (~500) + bilinear
//  VALU (~400) + MFMA + barrier, with nothing to overlap (1 block/CU, all
//  waves barrier-synced). R16 keeps R13's exact schedule (plain loads,
//  __syncthreads, 2-ahead register prefetch in source) and changes ONLY
//  geometry: BM 64->32, grid 512 -> 2 independent barrier domains per CU
//  (m114: block-level TLP is what actually hides latency). Sampling work is
//  not duplicated (M-split); B re-reads stay L2-resident.
//  K0 prep_and_transpose, K1 offset_conv_sk, K2 index_prep unchanged.
//  Workspace ~31 MB.

#define CIN 256
#define COUT 256
#define HWS 4096      // H*W
#define MTOT 16384    // B*H*W
#define KTOT 2304     // CIN*9
#define SPLITK 8

typedef __attribute__((ext_vector_type(8))) short bf16x8;
typedef __attribute__((ext_vector_type(4))) float f32x4;

__device__ __forceinline__ unsigned short f2bf(float f) {
  unsigned int u = __float_as_uint(f);
  unsigned int r = (u + 0x7fffu + ((u >> 16) & 1u)) >> 16;
  return (unsigned short)r;
}
__device__ __forceinline__ float bf2f(unsigned short u) {
  return __uint_as_float(((unsigned int)u) << 16);
}

__device__ __forceinline__ void gload_lds16(const void* g, void* l) {
  __builtin_amdgcn_global_load_lds((const __attribute__((address_space(1))) void*)g,
                                   (__attribute__((address_space(3))) void*)l, 16, 0, 0);
}

// ---------------- K0: fused transpose + weight prep (WB2 frag-block order) ----------------
__global__ __launch_bounds__(256) void prep_and_transpose(const float* __restrict__ x,
                                                          const float* __restrict__ w,
                                                          const float* __restrict__ pw,
                                                          unsigned short* __restrict__ xt,
                                                          unsigned short* __restrict__ WB,
                                                          unsigned short* __restrict__ PWs,
                                                          unsigned short* __restrict__ zerop) {
  __shared__ float tile[32][33];
  int bid = blockIdx.x;
  if (bid < 4096) {
    int b = bid >> 10;
    int rest = bid & 1023;
    int hw0 = (rest & 127) * 32;
    int c0 = ((rest >> 7) & 7) * 32;
    int tx = threadIdx.x & 31, ty = threadIdx.x >> 5;
    for (int i = ty; i < 32; i += 8)
      tile[i][tx] = x[(size_t)(b * CIN + c0 + i) * HWS + hw0 + tx];
    __syncthreads();
    for (int r = ty; r < 32; r += 8)
      xt[(size_t)(b * HWS + hw0 + r) * CIN + c0 + tx] = f2bf(tile[tx][r]);
  } else {
    int idx = (bid - 4096) * 256 + threadIdx.x;
    if (idx < 512)
      *(uint4*)(zerop + idx * 8) = make_uint4(0, 0, 0, 0);
    if (idx < KTOT * COUT) {
      // WB2[t][j][quad][row][8]: f = (((t*16+j)*4+quad)*16+row)*8+e
      int f = idx;
      int e = f & 7;
      int row = (f >> 3) & 15;
      int quad = (f >> 7) & 3;
      int j = (f >> 9) & 15;
      int t = f >> 13;                 // 0..71
      int kk = t * 32 + quad * 8 + e;
      int o = j * 16 + row;
      int k = kk >> 8, c = kk & 255;
      WB[f] = f2bf(w[o * KTOT + c * 9 + k]);
    } else {
      int f2 = idx - KTOT * COUT;   // < 2304*32
      int t_ = f2 & 7;
      int rest = f2 >> 3;
      int j = rest & 31;
      int kk = (rest >> 5) * 8 + t_;
      int k = kk >> 8, c = kk & 255;
      float v = (j < 27) ? pw[j * KTOT + c * 9 + k] : 0.0f;
      PWs[f2] = f2bf(v);
    }
  }
}

// ---------------- K1: offset conv, split-K, BM=64 ----------------
__global__ __launch_bounds__(256) void offset_conv_sk(const unsigned short* __restrict__ xt,
                                                      const unsigned short* __restrict__ PWs,
                                                      const unsigned short* __restrict__ zerop,
                                                      float* __restrict__ Pbuf) {
  __shared__ unsigned short Al[64 * 32];   // 4 KB
  __shared__ unsigned short Bl[1024];      // 2 KB
  int tid = threadIdx.x;
  int lane = tid & 63, wv = tid >> 6;
  int mt = (blockIdx.x & 7) * 32 + (blockIdx.x >> 3);   // XCD swizzle
  int m0 = mt * 64;
  int s = blockIdx.y;
  int b = m0 >> 12;
  int hw0 = m0 & 4095;
  f32x4 acc[2] = {};

  for (int tt = 0; tt < 72 / SPLITK; ++tt) {
    int t = s * (72 / SPLITK) + tt;
    int k = t >> 3, c0 = (t & 7) * 32;
    int dyk = k / 3 - 1;
    int dxk = k % 3 - 1;
    __syncthreads();
    if (tid < 128)
      gload_lds16(PWs + (size_t)t * 1024 + tid * 8, &Bl[tid * 8]);
    {
      int r = tid >> 2;
      int hw = hw0 + r;
      int h = hw >> 6, wwp = hw & 63;
      int y = h + dyk, xx = wwp + dxk;
      bool valid = ((unsigned)y < 64u) && ((unsigned)xx < 64u);
      const unsigned short* src = valid
          ? xt + ((size_t)((b << 12) + (y << 6) + xx) << 8) + c0 + (tid & 3) * 8
          : zerop;
      gload_lds16(src, &Al[tid * 8]);
    }
    __syncthreads();
    int row = lane & 15, quad = lane >> 4;
    bf16x8 af = *(const bf16x8*)&Al[(wv * 16 + row) * 32 + quad * 8];
    for (int j = 0; j < 2; ++j) {
      bf16x8 bfr = *(const bf16x8*)&Bl[(quad * 32 + j * 16 + row) * 8];
      acc[j] = __builtin_amdgcn_mfma_f32_16x16x32_bf16(af, bfr, acc[j], 0, 0, 0);
    }
  }

  int row = lane & 15, quad = lane >> 4;
  for (int j = 0; j < 2; ++j) {
    int n = j * 16 + row;
    for (int r_ = 0; r_ < 4; ++r_) {
      int m = m0 + wv * 16 + quad * 4 + r_;
      Pbuf[((size_t)s * MTOT + m) * 32 + n] = acc[j][r_];
    }
  }
}

// ---------------- K2: index prep — reduce Pbuf, compute corner idx + weights ----------------
// DIW layout: per (m, k): { int4 dI (elem offsets), float4 dW (corner weights*mask) }
__global__ __launch_bounds__(256) void index_prep(const float* __restrict__ Pbuf,
                                                  const float* __restrict__ p_bias,
                                                  int4* __restrict__ DIW) {
  int gid = blockIdx.x * 256 + threadIdx.x;   // 0..147455 == 16384*9
  int m = gid / 9;
  int k = gid - m * 9;

  float dy = p_bias[2 * k];
  float dx = p_bias[2 * k + 1];
  float mv = p_bias[18 + k];
#pragma unroll
  for (int s = 0; s < SPLITK; ++s) {
    const float* p = Pbuf + ((size_t)s * MTOT + m) * 32;
    dy += p[2 * k];
    dx += p[2 * k + 1];
    mv += p[18 + k];
  }
  float mk = 1.0f / (1.0f + __expf(-mv));

  int hw = m & 4095, h = hw >> 6, ww = hw & 63;
  float py = (float)(h - 1 + k / 3) + dy;
  float px = (float)(ww - 1 + k % 3) + dx;
  float y0f = floorf(py), x0f = floorf(px);
  float ay = py - y0f, ax = px - x0f;
  int y0 = (int)y0f, x0 = (int)x0f;

  float w00 = (1.f - ay) * (1.f - ax) * mk;
  float w01 = (1.f - ay) * ax * mk;
  float w10 = ay * (1.f - ax) * mk;
  float w11 = ay * ax * mk;

  float vy0 = ((unsigned)y0 < 64u) ? 1.f : 0.f;
  float vy1 = ((unsigned)(y0 + 1) < 64u) ? 1.f : 0.f;
  float vx0 = ((unsigned)x0 < 64u) ? 1.f : 0.f;
  float vx1 = ((unsigned)(x0 + 1) < 64u) ? 1.f : 0.f;
  w00 *= vy0 * vx0; w01 *= vy0 * vx1; w10 *= vy1 * vx0; w11 *= vy1 * vx1;

  int yc0 = min(max(y0, 0), 63), yc1 = min(max(y0 + 1, 0), 63);
  int xc0 = min(max(x0, 0), 63), xc1 = min(max(x0 + 1, 0), 63);

  DIW[(size_t)gid * 2] = make_int4((yc0 * 64 + xc0) * 256, (yc0 * 64 + xc1) * 256,
                                   (yc1 * 64 + xc0) * 256, (yc1 * 64 + xc1) * 256);
  float4 w4 = make_float4(w00, w01, w10, w11);
  ((float4*)DIW)[(size_t)gid * 2 + 1] = w4;
}

// ---------------- K3: fused sample + GEMM, BM=32, 2 blocks/CU ----------------
// Block: 32 m-rows x 256 cols, 256 threads (4 waves, wave = 32 rows x 64 cols).
// Grid 512 -> 2 blocks/CU: two independent barrier domains interleave their
// gather-latency stalls (the actual latency-hiding mechanism; R13-R15 showed
// source-level pipelining can't do it inside one lockstep block).
__device__ __forceinline__ void bilin4(const ushort4 g00, const ushort4 g01,
                                       const ushort4 g10, const ushort4 g11,
                                       const float4 w4, unsigned short* dst) {
  ushort4 o;
  o.x = f2bf(w4.x * bf2f(g00.x) + w4.y * bf2f(g01.x) + w4.z * bf2f(g10.x) + w4.w * bf2f(g11.x));
  o.y = f2bf(w4.x * bf2f(g00.y) + w4.y * bf2f(g01.y) + w4.z * bf2f(g10.y) + w4.w * bf2f(g11.y));
  o.z = f2bf(w4.x * bf2f(g00.z) + w4.y * bf2f(g01.z) + w4.z * bf2f(g10.z) + w4.w * bf2f(g11.z));
  o.w = f2bf(w4.x * bf2f(g00.w) + w4.y * bf2f(g01.w) + w4.z * bf2f(g10.w) + w4.w * bf2f(g11.w));
  *(ushort4*)dst = o;
}

#define MFMA8(A0, A1, B0, B1, B2, B3)                                                    \
  acc[0][0] = __builtin_amdgcn_mfma_f32_16x16x32_bf16(A0, B0, acc[0][0], 0, 0, 0);       \
  acc[0][1] = __builtin_amdgcn_mfma_f32_16x16x32_bf16(A0, B1, acc[0][1], 0, 0, 0);       \
  acc[0][2] = __builtin_amdgcn_mfma_f32_16x16x32_bf16(A0, B2, acc[0][2], 0, 0, 0);       \
  acc[0][3] = __builtin_amdgcn_mfma_f32_16x16x32_bf16(A0, B3, acc[0][3], 0, 0, 0);       \
  acc[1][0] = __builtin_amdgcn_mfma_f32_16x16x32_bf16(A1, B0, acc[1][0], 0, 0, 0);       \
  acc[1][1] = __builtin_amdgcn_mfma_f32_16x16x32_bf16(A1, B1, acc[1][1], 0, 0, 0);       \
  acc[1][2] = __builtin_amdgcn_mfma_f32_16x16x32_bf16(A1, B2, acc[1][2], 0, 0, 0);       \
  acc[1][3] = __builtin_amdgcn_mfma_f32_16x16x32_bf16(A1, B3, acc[1][3], 0, 0, 0);

// Tile body T (PAR = T&1 literal). R13 schedule verbatim, BM=32 geometry:
//  a) plain-load gathers(T+2) [dI4 advanced at (T+2)&7==0, one tap AHEAD of dW4]
//  b) plain-load B(T+1) -> BN*
//  c) ds_read A-frags(T)
//  d) bilin4(T+1) -> As[PAR^1]  [dW4 advanced at (T+1)&7==0]
//  e) 8 MFMA
//  f) __syncthreads
#define FITER(T, PAR, BC0, BC1, BC2, BC3, BN0, BN1, BN2, BN3)                            \
  {                                                                                      \
    if ((T) <= 69) {                                                                     \
      if ((((T) + 2) & 7) == 0) dI4 = Tbl[r][((T) + 2) >> 3][0];                         \
      int cq = (((T) + 2) & 7) * 32 + qo;                                                \
      g00 = *(const ushort4*)(xtb + dI4.x + cq);                                         \
      g01 = *(const ushort4*)(xtb + dI4.y + cq);                                         \
      g10 = *(const ushort4*)(xtb + dI4.z + cq);                                         \
      g11 = *(const ushort4*)(xtb + dI4.w + cq);                                         \
    }                                                                                    \
    if ((T) <= 70) {                                                                     \
      const unsigned short* bt_ = bpb + (size_t)((T) + 1) * 8192;                        \
      BN0 = *(const bf16x8*)(bt_);                                                       \
      BN1 = *(const bf16x8*)(bt_ + 512);                                                 \
      BN2 = *(const bf16x8*)(bt_ + 1024);                                                \
      BN3 = *(const bf16x8*)(bt_ + 1536);                                                \
    }                                                                                    \
    afr0 = *(const bf16x8*)&As[PAR][row][quad * 8];                                      \
    afr1 = *(const bf16x8*)&As[PAR][16 + row][quad * 8];                                 \
    if ((T) <= 70) {                                                                     \
      if ((((T) + 1) & 7) == 0) dW4 = *(float4*)&Tbl[r][((T) + 1) >> 3][1];              \
      bilin4(gp0, gp1, gp2, gp3, dW4, &As[PAR ^ 1][r][qo]);                              \
    }                                                                                    \
    MFMA8(afr0, afr1, BC0, BC1, BC2, BC3)                                                \
    __syncthreads();                                                                     \
  }

__global__ __launch_bounds__(256, 2) void fused_gemm(const unsigned short* __restrict__ xt,
                                                     const int4* __restrict__ DIW,
                                                     const unsigned short* __restrict__ WB,
                                                     const float* __restrict__ bias,
                                                     float* __restrict__ out) {
  __shared__ unsigned short As[2][32][40];   // 5,120 B (padded +8)
  __shared__ int4 Tbl[32][9][2];             // 9,216 B [r][tap]{dI, dW}

  int tid = threadIdx.x;
  int lane = tid & 63, wv = tid >> 6;
  // XCD-chunked swizzle: XCD x gets 64 consecutive m-tiles (2048 m-rows).
  int mt = (blockIdx.x & 7) * 64 + (blockIdx.x >> 3);
  int mb = mt * 32;
  int b = mb >> 12;
  int hw0 = mb & 4095;
  const unsigned short* xtb = xt + ((size_t)b << 20);

  // stage index/weight table for this block's 32 rows (576 int4, contiguous)
  {
    const int4* src = DIW + (size_t)mb * 18;
    int4* dst = (int4*)Tbl;
    for (int i = tid; i < 576; i += 256)
      gload_lds16(src + i, dst + i);
  }
  __syncthreads();   // drains global_load_lds staging — once

  int r = tid >> 3;        // sampler row 0..31 (8 threads/row)
  int qo = (tid & 7) * 4;  // sampler channel sub-block (4 ch)

  int4 dI4 = Tbl[r][0][0];
  float4 dW4 = *(float4*)&Tbl[r][0][1];

  int row = lane & 15, quad = lane >> 4;
  const unsigned short* bpb = WB + (size_t)wv * 4 * 512 + quad * 128 + row * 8;

  f32x4 acc[2][4] = {};
  ushort4 g00, g01, g10, g11;          // in-flight gathers (next-next tile)
  ushort4 gp0, gp1, gp2, gp3;          // gathers pending consumption (next tile)
  bf16x8 bA0, bA1, bA2, bA3, bB0, bB1, bB2, bB3;
  bf16x8 afr0, afr1;

  // ---- prologue: sample tile 0 directly, load B(0), issue gathers(1) ----
  {
    g00 = *(const ushort4*)(xtb + dI4.x + qo);
    g01 = *(const ushort4*)(xtb + dI4.y + qo);
    g10 = *(const ushort4*)(xtb + dI4.z + qo);
    g11 = *(const ushort4*)(xtb + dI4.w + qo);
    bA0 = *(const bf16x8*)(bpb);
    bA1 = *(const bf16x8*)(bpb + 512);
    bA2 = *(const bf16x8*)(bpb + 1024);
    bA3 = *(const bf16x8*)(bpb + 1536);
    bilin4(g00, g01, g10, g11, dW4, &As[0][r][qo]);
    // gathers for tile 1 (tap 0, c0 = 32)
    g00 = *(const ushort4*)(xtb + dI4.x + 32 + qo);
    g01 = *(const ushort4*)(xtb + dI4.y + 32 + qo);
    g10 = *(const ushort4*)(xtb + dI4.z + 32 + qo);
    g11 = *(const ushort4*)(xtb + dI4.w + 32 + qo);
  }
  __syncthreads();

#pragma unroll 1
  for (int t = 0; t < 72; t += 2) {
    gp0 = g00; gp1 = g01; gp2 = g10; gp3 = g11;
    FITER(t, 0, bA0, bA1, bA2, bA3, bB0, bB1, bB2, bB3)
    gp0 = g00; gp1 = g01; gp2 = g10; gp3 = g11;
    FITER(t + 1, 1, bB0, bB1, bB2, bB3, bA0, bA1, bA2, bA3)
  }

  // ---- epilogue: add bias, store NCHW ----
#pragma unroll
  for (int j = 0; j < 4; ++j) {
    int o = wv * 64 + j * 16 + row;
    float bo = bias[o];
#pragma unroll
    for (int i = 0; i < 2; ++i) {
      int hw = hw0 + i * 16 + quad * 4;
      float4 v;
      v.x = acc[i][j][0] + bo;
      v.y = acc[i][j][1] + bo;
      v.z = acc[i][j][2] + bo;
      v.w = acc[i][j][3] + bo;
      *(float4*)(out + (((size_t)(b * COUT + o)) << 12) + hw) = v;
    }
  }
}

// ---------------- launch ----------------
extern "C" void kernel_launch(void* const* d_in, const int* in_sizes, int n_in,
                              void* d_out, int out_size, void* d_ws, size_t ws_size,
                              hipStream_t stream) {
  const float* x        = (const float*)d_in[0];
  const float* weight   = (const float*)d_in[1];
  const float* bias     = (const float*)d_in[2];
  const float* p_weight = (const float*)d_in[3];
  const float* p_bias   = (const float*)d_in[4];
  float* out = (float*)d_out;
  char* ws = (char*)d_ws;

  // workspace layout (bytes); total ~31 MB
  const size_t OFF_XT   = 0;                          //  8,388,608  bf16 NHWC x
  const size_t OFF_WB   = OFF_XT + 8388608;           //  1,179,648  bf16 WB2
  const size_t OFF_PW   = OFF_WB + 1179648;           //    147,456  bf16
  const size_t OFF_P    = OFF_PW + 147456;            // 16,777,216  fp32 partials
  const size_t OFF_ZP   = OFF_P + 16777216;           //      8,192  zeropage
  const size_t OFF_DIW  = OFF_ZP + 8192;              //  4,718,592  idx/weight table

  unsigned short* xt    = (unsigned short*)(ws + OFF_XT);
  unsigned short* WB    = (unsigned short*)(ws + OFF_WB);
  unsigned short* PWs   = (unsigned short*)(ws + OFF_PW);
  float* Pbuf           = (float*)(ws + OFF_P);
  unsigned short* zerop = (unsigned short*)(ws + OFF_ZP);
  int4* DIW             = (int4*)(ws + OFF_DIW);

  prep_and_transpose<<<4096 + 2592, 256, 0, stream>>>(x, weight, p_weight, xt, WB, PWs, zerop);
  offset_conv_sk<<<dim3(MTOT / 64, SPLITK), 256, 0, stream>>>(xt, PWs, zerop, Pbuf);
  index_prep<<<576, 256, 0, stream>>>(Pbuf, p_bias, DIW);
  fused_gemm<<<512, 256, 0, stream>>>(xt, DIW, WB, bias, out);
}

// Round 6
// 146.680 us; speedup vs baseline: 1.0740x; 1.0049x over previous
//
#include <hip/hip_runtime.h>
#include <stdint.h>

// DCNv2 forward, MI355X — R17b: tap-major fused_gemm, barriers 72 -> 10.
//  (Resubmission of R17 — round 5 died to container acquire failure, no data.)
//  R13-R16 post-mortems: R13 (50.6us) is locally optimal GIVEN its barrier
//  granularity; barrier type (R14), pinning/waves (R15), and block TLP (R16)
//  all regressed. The untouched invariant: 72 per-k-tile barriers chop the
//  stream into ~1700cy lockstep chunks; the compiler cannot hoist loads
//  across barriers, so gather latency is paid 72 times.
//  R17: tap-major double-buffer. As holds a FULL tap (64 rows x 256 ch,
//  33KB) x2; per tap: consume 8 k-tiles (ds_read A + global B + 16 MFMA,
//  barrier-free) while producing tap+1 (gather+bilinear+ds_write) inline in
//  the same region; ONE __syncthreads per tap. Compiler hoists freely inside
//  the ~13k-cy region (m97 lesson: it schedules well within regions).
//  LDS 86KB -> 1 block/CU, 4 waves; overlap is intra-region ILP.
//  K0 prep_and_transpose, K1 offset_conv_sk, K2 index_prep unchanged.

#define CIN 256
#define COUT 256
#define HWS 4096      // H*W
#define MTOT 16384    // B*H*W
#define KTOT 2304     // CIN*9
#define SPLITK 8

typedef __attribute__((ext_vector_type(8))) short bf16x8;
typedef __attribute__((ext_vector_type(4))) float f32x4;

__device__ __forceinline__ unsigned short f2bf(float f) {
  unsigned int u = __float_as_uint(f);
  unsigned int r = (u + 0x7fffu + ((u >> 16) & 1u)) >> 16;
  return (unsigned short)r;
}
__device__ __forceinline__ float bf2f(unsigned short u) {
  return __uint_as_float(((unsigned int)u) << 16);
}

__device__ __forceinline__ void gload_lds16(const void* g, void* l) {
  __builtin_amdgcn_global_load_lds((const __attribute__((address_space(1))) void*)g,
                                   (__attribute__((address_space(3))) void*)l, 16, 0, 0);
}

// ---------------- K0: fused transpose + weight prep (WB2 frag-block order) ----------------
__global__ __launch_bounds__(256) void prep_and_transpose(const float* __restrict__ x,
                                                          const float* __restrict__ w,
                                                          const float* __restrict__ pw,
                                                          unsigned short* __restrict__ xt,
                                                          unsigned short* __restrict__ WB,
                                                          unsigned short* __restrict__ PWs,
                                                          unsigned short* __restrict__ zerop) {
  __shared__ float tile[32][33];
  int bid = blockIdx.x;
  if (bid < 4096) {
    int b = bid >> 10;
    int rest = bid & 1023;
    int hw0 = (rest & 127) * 32;
    int c0 = ((rest >> 7) & 7) * 32;
    int tx = threadIdx.x & 31, ty = threadIdx.x >> 5;
    for (int i = ty; i < 32; i += 8)
      tile[i][tx] = x[(size_t)(b * CIN + c0 + i) * HWS + hw0 + tx];
    __syncthreads();
    for (int r = ty; r < 32; r += 8)
      xt[(size_t)(b * HWS + hw0 + r) * CIN + c0 + tx] = f2bf(tile[tx][r]);
  } else {
    int idx = (bid - 4096) * 256 + threadIdx.x;
    if (idx < 512)
      *(uint4*)(zerop + idx * 8) = make_uint4(0, 0, 0, 0);
    if (idx < KTOT * COUT) {
      // WB2[t][j][quad][row][8]: f = (((t*16+j)*4+quad)*16+row)*8+e
      int f = idx;
      int e = f & 7;
      int row = (f >> 3) & 15;
      int quad = (f >> 7) & 3;
      int j = (f >> 9) & 15;
      int t = f >> 13;                 // 0..71
      int kk = t * 32 + quad * 8 + e;
      int o = j * 16 + row;
      int k = kk >> 8, c = kk & 255;
      WB[f] = f2bf(w[o * KTOT + c * 9 + k]);
    } else {
      int f2 = idx - KTOT * COUT;   // < 2304*32
      int t_ = f2 & 7;
      int rest = f2 >> 3;
      int j = rest & 31;
      int kk = (rest >> 5) * 8 + t_;
      int k = kk >> 8, c = kk & 255;
      float v = (j < 27) ? pw[j * KTOT + c * 9 + k] : 0.0f;
      PWs[f2] = f2bf(v);
    }
  }
}

// ---------------- K1: offset conv, split-K, BM=64 ----------------
__global__ __launch_bounds__(256) void offset_conv_sk(const unsigned short* __restrict__ xt,
                                                      const unsigned short* __restrict__ PWs,
                                                      const unsigned short* __restrict__ zerop,
                                                      float* __restrict__ Pbuf) {
  __shared__ unsigned short Al[64 * 32];   // 4 KB
  __shared__ unsigned short Bl[1024];      // 2 KB
  int tid = threadIdx.x;
  int lane = tid & 63, wv = tid >> 6;
  int mt = (blockIdx.x & 7) * 32 + (blockIdx.x >> 3);   // XCD swizzle
  int m0 = mt * 64;
  int s = blockIdx.y;
  int b = m0 >> 12;
  int hw0 = m0 & 4095;
  f32x4 acc[2] = {};

  for (int tt = 0; tt < 72 / SPLITK; ++tt) {
    int t = s * (72 / SPLITK) + tt;
    int k = t >> 3, c0 = (t & 7) * 32;
    int dyk = k / 3 - 1;
    int dxk = k % 3 - 1;
    __syncthreads();
    if (tid < 128)
      gload_lds16(PWs + (size_t)t * 1024 + tid * 8, &Bl[tid * 8]);
    {
      int r = tid >> 2;
      int hw = hw0 + r;
      int h = hw >> 6, wwp = hw & 63;
      int y = h + dyk, xx = wwp + dxk;
      bool valid = ((unsigned)y < 64u) && ((unsigned)xx < 64u);
      const unsigned short* src = valid
          ? xt + ((size_t)((b << 12) + (y << 6) + xx) << 8) + c0 + (tid & 3) * 8
          : zerop;
      gload_lds16(src, &Al[tid * 8]);
    }
    __syncthreads();
    int row = lane & 15, quad = lane >> 4;
    bf16x8 af = *(const bf16x8*)&Al[(wv * 16 + row) * 32 + quad * 8];
    for (int j = 0; j < 2; ++j) {
      bf16x8 bfr = *(const bf16x8*)&Bl[(quad * 32 + j * 16 + row) * 8];
      acc[j] = __builtin_amdgcn_mfma_f32_16x16x32_bf16(af, bfr, acc[j], 0, 0, 0);
    }
  }

  int row = lane & 15, quad = lane >> 4;
  for (int j = 0; j < 2; ++j) {
    int n = j * 16 + row;
    for (int r_ = 0; r_ < 4; ++r_) {
      int m = m0 + wv * 16 + quad * 4 + r_;
      Pbuf[((size_t)s * MTOT + m) * 32 + n] = acc[j][r_];
    }
  }
}

// ---------------- K2: index prep — reduce Pbuf, compute corner idx + weights ----------------
// DIW layout: per (m, k): { int4 dI (elem offsets), float4 dW (corner weights*mask) }
__global__ __launch_bounds__(256) void index_prep(const float* __restrict__ Pbuf,
                                                  const float* __restrict__ p_bias,
                                                  int4* __restrict__ DIW) {
  int gid = blockIdx.x * 256 + threadIdx.x;   // 0..147455 == 16384*9
  int m = gid / 9;
  int k = gid - m * 9;

  float dy = p_bias[2 * k];
  float dx = p_bias[2 * k + 1];
  float mv = p_bias[18 + k];
#pragma unroll
  for (int s = 0; s < SPLITK; ++s) {
    const float* p = Pbuf + ((size_t)s * MTOT + m) * 32;
    dy += p[2 * k];
    dx += p[2 * k + 1];
    mv += p[18 + k];
  }
  float mk = 1.0f / (1.0f + __expf(-mv));

  int hw = m & 4095, h = hw >> 6, ww = hw & 63;
  float py = (float)(h - 1 + k / 3) + dy;
  float px = (float)(ww - 1 + k % 3) + dx;
  float y0f = floorf(py), x0f = floorf(px);
  float ay = py - y0f, ax = px - x0f;
  int y0 = (int)y0f, x0 = (int)x0f;

  float w00 = (1.f - ay) * (1.f - ax) * mk;
  float w01 = (1.f - ay) * ax * mk;
  float w10 = ay * (1.f - ax) * mk;
  float w11 = ay * ax * mk;

  float vy0 = ((unsigned)y0 < 64u) ? 1.f : 0.f;
  float vy1 = ((unsigned)(y0 + 1) < 64u) ? 1.f : 0.f;
  float vx0 = ((unsigned)x0 < 64u) ? 1.f : 0.f;
  float vx1 = ((unsigned)(x0 + 1) < 64u) ? 1.f : 0.f;
  w00 *= vy0 * vx0; w01 *= vy0 * vx1; w10 *= vy1 * vx0; w11 *= vy1 * vx1;

  int yc0 = min(max(y0, 0), 63), yc1 = min(max(y0 + 1, 0), 63);
  int xc0 = min(max(x0, 0), 63), xc1 = min(max(x0 + 1, 0), 63);

  DIW[(size_t)gid * 2] = make_int4((yc0 * 64 + xc0) * 256, (yc0 * 64 + xc1) * 256,
                                   (yc1 * 64 + xc0) * 256, (yc1 * 64 + xc1) * 256);
  float4 w4 = make_float4(w00, w01, w10, w11);
  ((float4*)DIW)[(size_t)gid * 2 + 1] = w4;
}

// ---------------- K3: fused sample + GEMM, tap-major double-buffer ----------------
// Block: 64 m-rows x 256 cols, 256 threads (4 waves, wave = 64 rows x 64 cols,
// N-split). As[2] holds full taps (64 x 256ch, +8 pad). Per tap: 8 barrier-free
// k-tiles consumed from As[cur] while tap+1 is produced into As[cur^1].
__device__ __forceinline__ void bilin8(const bf16x8 g00, const bf16x8 g01,
                                       const bf16x8 g10, const bf16x8 g11,
                                       const float4 w4, unsigned short* dst) {
  bf16x8 o8;
#pragma unroll
  for (int e = 0; e < 8; ++e) {
    float v = w4.x * bf2f((unsigned short)g00[e]) + w4.y * bf2f((unsigned short)g01[e]) +
              w4.z * bf2f((unsigned short)g10[e]) + w4.w * bf2f((unsigned short)g11[e]);
    o8[e] = (short)f2bf(v);
  }
  *(bf16x8*)dst = o8;
}

#define MFMA16(A0, A1, A2_, A3, B0, B1, B2, B3)                                          \
  acc[0][0] = __builtin_amdgcn_mfma_f32_16x16x32_bf16(A0, B0, acc[0][0], 0, 0, 0);       \
  acc[0][1] = __builtin_amdgcn_mfma_f32_16x16x32_bf16(A0, B1, acc[0][1], 0, 0, 0);       \
  acc[0][2] = __builtin_amdgcn_mfma_f32_16x16x32_bf16(A0, B2, acc[0][2], 0, 0, 0);       \
  acc[0][3] = __builtin_amdgcn_mfma_f32_16x16x32_bf16(A0, B3, acc[0][3], 0, 0, 0);       \
  acc[1][0] = __builtin_amdgcn_mfma_f32_16x16x32_bf16(A1, B0, acc[1][0], 0, 0, 0);       \
  acc[1][1] = __builtin_amdgcn_mfma_f32_16x16x32_bf16(A1, B1, acc[1][1], 0, 0, 0);       \
  acc[1][2] = __builtin_amdgcn_mfma_f32_16x16x32_bf16(A1, B2, acc[1][2], 0, 0, 0);       \
  acc[1][3] = __builtin_amdgcn_mfma_f32_16x16x32_bf16(A1, B3, acc[1][3], 0, 0, 0);       \
  acc[2][0] = __builtin_amdgcn_mfma_f32_16x16x32_bf16(A2_, B0, acc[2][0], 0, 0, 0);      \
  acc[2][1] = __builtin_amdgcn_mfma_f32_16x16x32_bf16(A2_, B1, acc[2][1], 0, 0, 0);      \
  acc[2][2] = __builtin_amdgcn_mfma_f32_16x16x32_bf16(A2_, B2, acc[2][2], 0, 0, 0);      \
  acc[2][3] = __builtin_amdgcn_mfma_f32_16x16x32_bf16(A2_, B3, acc[2][3], 0, 0, 0);      \
  acc[3][0] = __builtin_amdgcn_mfma_f32_16x16x32_bf16(A3, B0, acc[3][0], 0, 0, 0);       \
  acc[3][1] = __builtin_amdgcn_mfma_f32_16x16x32_bf16(A3, B1, acc[3][1], 0, 0, 0);       \
  acc[3][2] = __builtin_amdgcn_mfma_f32_16x16x32_bf16(A3, B2, acc[3][2], 0, 0, 0);       \
  acc[3][3] = __builtin_amdgcn_mfma_f32_16x16x32_bf16(A3, B3, acc[3][3], 0, 0, 0);

__global__ __launch_bounds__(256, 1) void fused_gemm(const unsigned short* __restrict__ xt,
                                                     const int4* __restrict__ DIW,
                                                     const unsigned short* __restrict__ WB,
                                                     const float* __restrict__ bias,
                                                     float* __restrict__ out) {
  __shared__ unsigned short As[2][64][264];  // 67,584 B: full tap x2, +8ch pad
  __shared__ int4 Tbl[64][9][2];             // 18,432 B [r][tap]{dI, dW}

  int tid = threadIdx.x;
  int lane = tid & 63, wv = tid >> 6;
  // XCD-chunked swizzle: XCD x gets 32 consecutive m-tiles (2048 m-rows).
  int mt = (blockIdx.x & 7) * 32 + (blockIdx.x >> 3);
  int mb = mt * 64;
  int b = mb >> 12;
  int hw0 = mb & 4095;
  const unsigned short* xtb = xt + ((size_t)b << 20);

  // stage index/weight table for this block's 64 rows (1152 int4)
  {
    const int4* src = DIW + (size_t)mb * 18;
    int4* dst = (int4*)Tbl;
    for (int i = tid; i < 1152; i += 256)
      gload_lds16(src + i, dst + i);
  }
  __syncthreads();   // drains global_load_lds staging

  int r = tid >> 2;        // producer row 0..63
  int sl = tid & 3;        // producer channel slot (8 ch each, stride 32)

  int row = lane & 15, quad = lane >> 4;
  const unsigned short* bpb = WB + (size_t)wv * 4 * 512 + quad * 128 + row * 8;

  f32x4 acc[4][4] = {};
  bf16x8 afr0, afr1, afr2, afr3, bfr0, bfr1, bfr2, bfr3;
  bf16x8 g00, g01, g10, g11;

  // ---- prologue: produce tap 0 into As[0] ----
  {
    int4 dI0 = Tbl[r][0][0];
    float4 dW0 = *(float4*)&Tbl[r][0][1];
#pragma unroll
    for (int j = 0; j < 8; ++j) {
      int ch = sl * 8 + j * 32;
      g00 = *(const bf16x8*)(xtb + dI0.x + ch);
      g01 = *(const bf16x8*)(xtb + dI0.y + ch);
      g10 = *(const bf16x8*)(xtb + dI0.z + ch);
      g11 = *(const bf16x8*)(xtb + dI0.w + ch);
      bilin8(g00, g01, g10, g11, dW0, &As[0][r][ch]);
    }
  }
  __syncthreads();

  // ---- main: 9 taps; consume As[tap&1], produce tap+1 into As[(tap&1)^1] ----
#pragma unroll 1
  for (int tap = 0; tap < 9; ++tap) {
    int cur = tap & 1;
    bool prod = tap < 8;
    int4 dI4n;
    float4 dW4n;
    if (prod) {
      dI4n = Tbl[r][tap + 1][0];
      dW4n = *(float4*)&Tbl[r][tap + 1][1];
    }
    const unsigned short* btap = bpb + (size_t)tap * 65536;   // 8 k-tiles * 8192
#pragma unroll
    for (int j = 0; j < 8; ++j) {
      const unsigned short* bt_ = btap + j * 8192;
      bfr0 = *(const bf16x8*)(bt_);
      bfr1 = *(const bf16x8*)(bt_ + 512);
      bfr2 = *(const bf16x8*)(bt_ + 1024);
      bfr3 = *(const bf16x8*)(bt_ + 1536);
      int ac = j * 32 + quad * 8;
      afr0 = *(const bf16x8*)&As[cur][row][ac];
      afr1 = *(const bf16x8*)&As[cur][16 + row][ac];
      afr2 = *(const bf16x8*)&As[cur][32 + row][ac];
      afr3 = *(const bf16x8*)&As[cur][48 + row][ac];
      if (prod) {
        int ch = sl * 8 + j * 32;
        g00 = *(const bf16x8*)(xtb + dI4n.x + ch);
        g01 = *(const bf16x8*)(xtb + dI4n.y + ch);
        g10 = *(const bf16x8*)(xtb + dI4n.z + ch);
        g11 = *(const bf16x8*)(xtb + dI4n.w + ch);
      }
      MFMA16(afr0, afr1, afr2, afr3, bfr0, bfr1, bfr2, bfr3)
      if (prod) {
        bilin8(g00, g01, g10, g11, dW4n, &As[cur ^ 1][r][sl * 8 + j * 32]);
      }
    }
    __syncthreads();
  }

  // ---- epilogue: add bias, store NCHW ----
#pragma unroll
  for (int j = 0; j < 4; ++j) {
    int o = wv * 64 + j * 16 + row;
    float bo = bias[o];
#pragma unroll
    for (int i = 0; i < 4; ++i) {
      int hw = hw0 + i * 16 + quad * 4;
      float4 v;
      v.x = acc[i][j][0] + bo;
      v.y = acc[i][j][1] + bo;
      v.z = acc[i][j][2] + bo;
      v.w = acc[i][j][3] + bo;
      *(float4*)(out + (((size_t)(b * COUT + o)) << 12) + hw) = v;
    }
  }
}

// ---------------- launch ----------------
extern "C" void kernel_launch(void* const* d_in, const int* in_sizes, int n_in,
                              void* d_out, int out_size, void* d_ws, size_t ws_size,
                              hipStream_t stream) {
  const float* x        = (const float*)d_in[0];
  const float* weight   = (const float*)d_in[1];
  const float* bias     = (const float*)d_in[2];
  const float* p_weight = (const float*)d_in[3];
  const float* p_bias   = (const float*)d_in[4];
  float* out = (float*)d_out;
  char* ws = (char*)d_ws;

  // workspace layout (bytes); total ~31 MB
  const size_t OFF_XT   = 0;                          //  8,388,608  bf16 NHWC x
  const size_t OFF_WB   = OFF_XT + 8388608;           //  1,179,648  bf16 WB2
  const size_t OFF_PW   = OFF_WB + 1179648;           //    147,456  bf16
  const size_t OFF_P    = OFF_PW + 147456;            // 16,777,216  fp32 partials
  const size_t OFF_ZP   = OFF_P + 16777216;           //      8,192  zeropage
  const size_t OFF_DIW  = OFF_ZP + 8192;              //  4,718,592  idx/weight table

  unsigned short* xt    = (unsigned short*)(ws + OFF_XT);
  unsigned short* WB    = (unsigned short*)(ws + OFF_WB);
  unsigned short* PWs   = (unsigned short*)(ws + OFF_PW);
  float* Pbuf           = (float*)(ws + OFF_P);
  unsigned short* zerop = (unsigned short*)(ws + OFF_ZP);
  int4* DIW             = (int4*)(ws + OFF_DIW);

  prep_and_transpose<<<4096 + 2592, 256, 0, stream>>>(x, weight, p_weight, xt, WB, PWs, zerop);
  offset_conv_sk<<<dim3(MTOT / 64, SPLITK), 256, 0, stream>>>(xt, PWs, zerop, Pbuf);
  index_prep<<<576, 256, 0, stream>>>(Pbuf, p_bias, DIW);
  fused_gemm<<<256, 256, 0, stream>>>(xt, DIW, WB, bias, out);
}